// Round 6
// baseline (302.240 us; speedup 1.0000x reference)
//
#include <hip/hip_runtime.h>

#define USH unsigned short

using s8v = __attribute__((ext_vector_type(8))) short;   // 8 x bf16 (4 VGPR)
using f4v = __attribute__((ext_vector_type(4))) float;   // MFMA accumulator

#define MFMA16(a,b,c) __builtin_amdgcn_mfma_f32_16x16x32_bf16(a,b,c,0,0,0)

// dims: B=4, F=T=1024, C=1024, H=16, D=64

__device__ __forceinline__ USH f2bf(float f) {            // RNE f32->bf16
  unsigned int u = __builtin_bit_cast(unsigned int, f);
  u += 0x7fffu + ((u >> 16) & 1u);
  return (USH)(u >> 16);
}
__device__ __forceinline__ void gload16(const void* g, void* l) {
  __builtin_amdgcn_global_load_lds((const __attribute__((address_space(1))) void*)g,
                                   (__attribute__((address_space(3))) void*)l, 16, 0, 0);
}

// ---------------- conversion kernels ----------------
__global__ __launch_bounds__(256) void cvt_qkv_k(
    const float* __restrict__ q, const float* __restrict__ k, const float* __restrict__ v,
    USH* __restrict__ oq, USH* __restrict__ ok, USH* __restrict__ ov) {
  const int which = blockIdx.y;
  const float* in = which == 0 ? q : (which == 1 ? k : v);
  USH* out = which == 0 ? oq : (which == 1 ? ok : ov);
  const int i = blockIdx.x * 256 + threadIdx.x;           // n4 = 1<<20
  float4 val = ((const float4*)in)[i];
  ushort4 o; o.x = f2bf(val.x); o.y = f2bf(val.y); o.z = f2bf(val.z); o.w = f2bf(val.w);
  ((ushort4*)out)[i] = o;
}

__global__ __launch_bounds__(256) void cvt_w_k(
    const float* __restrict__ a, const float* __restrict__ b,
    const float* __restrict__ c, const float* __restrict__ d,
    USH* __restrict__ oa, USH* __restrict__ ob, USH* __restrict__ oc, USH* __restrict__ od) {
  const int which = blockIdx.y;
  const float* in = which == 0 ? a : which == 1 ? b : which == 2 ? c : d;
  USH* out = which == 0 ? oa : which == 1 ? ob : which == 2 ? oc : od;
  const int i = blockIdx.x * 256 + threadIdx.x;           // n4 = 262144
  float4 val = ((const float4*)in)[i];
  ushort4 o; o.x = f2bf(val.x); o.y = f2bf(val.y); o.z = f2bf(val.z); o.w = f2bf(val.w);
  ((ushort4*)out)[i] = o;
}

// ---------------- GEMM core: 128x128 tile, BK=32, K=1024, B^T layout ----------------
__device__ __forceinline__ void gemm_mainloop(
    const USH* __restrict__ A, const USH* __restrict__ W,
    int rowA0, int colW0, USH* As, USH* Bs, f4v acc[4][4], int tid) {
  const int lane = tid & 63;
  const int wid = tid >> 6;
  const int l15 = lane & 15, lg = lane >> 4;
  const int wr = (wid >> 1) * 64, wc = (wid & 1) * 64;
  for (int kk = 0; kk < 32; ++kk) {
    const int k0 = kk * 32;
    {                                                     // stage 8KB A + 8KB W
      const int c0 = tid, c1 = 256 + tid;
      gload16(A + (rowA0 + (c0 >> 2)) * 1024 + k0 + (c0 & 3) * 8, As + c0 * 8);
      gload16(A + (rowA0 + (c1 >> 2)) * 1024 + k0 + (c1 & 3) * 8, As + c1 * 8);
      gload16(W + (colW0 + (c0 >> 2)) * 1024 + k0 + (c0 & 3) * 8, Bs + c0 * 8);
      gload16(W + (colW0 + (c1 >> 2)) * 1024 + k0 + (c1 & 3) * 8, Bs + c1 * 8);
    }
    __syncthreads();
    s8v a[4], b[4];
    const USH* ap = As + (wr + l15) * 32 + lg * 8;
    const USH* bp = Bs + (wc + l15) * 32 + lg * 8;
#pragma unroll
    for (int m = 0; m < 4; ++m) a[m] = *(const s8v*)(ap + m * 512);
#pragma unroll
    for (int n = 0; n < 4; ++n) b[n] = *(const s8v*)(bp + n * 512);
#pragma unroll
    for (int m = 0; m < 4; ++m)
#pragma unroll
      for (int n = 0; n < 4; ++n)
        acc[m][n] = MFMA16(a[m], b[n], acc[m][n]);
    __syncthreads();
  }
}

// fused Q/K/V projection; z selects which. Q/K -> [B,H,S,64]; V -> [B,H,64,T] (transposed)
__global__ __launch_bounds__(256) void proj_gemm_k(
    const USH* __restrict__ qb, const USH* __restrict__ kb, const USH* __restrict__ vb,
    const USH* __restrict__ Wq, const USH* __restrict__ Wk, const USH* __restrict__ Wv,
    const float* __restrict__ bq, const float* __restrict__ bk, const float* __restrict__ bv,
    USH* __restrict__ qh, USH* __restrict__ kh, USH* __restrict__ vT) {
  __shared__ USH As[128 * 32];
  __shared__ USH Bs[128 * 32];
  const int z = blockIdx.z;
  const USH* A = z == 0 ? qb : (z == 1 ? kb : vb);
  const USH* W = z == 0 ? Wq : (z == 1 ? Wk : Wv);
  const float* bias = z == 0 ? bq : (z == 1 ? bk : bv);
  f4v acc[4][4];
#pragma unroll
  for (int m = 0; m < 4; ++m)
#pragma unroll
    for (int n = 0; n < 4; ++n) acc[m][n] = f4v{0.f, 0.f, 0.f, 0.f};
  gemm_mainloop(A, W, blockIdx.y * 128, blockIdx.x * 128, As, Bs, acc, threadIdx.x);
  const int lane = threadIdx.x & 63, wid = threadIdx.x >> 6;
  const int l15 = lane & 15, lg = lane >> 4;
  const int row0 = blockIdx.y * 128 + (wid >> 1) * 64 + lg * 4;
  const int col0 = blockIdx.x * 128 + (wid & 1) * 64 + l15;
  USH* qk_dst = (z == 0) ? qh : kh;
#pragma unroll
  for (int n = 0; n < 4; ++n) {
    const int co = col0 + n * 16;
    const float bsv = bias[co];
    const int hh = co >> 6, d = co & 63;
#pragma unroll
    for (int m = 0; m < 4; ++m)
#pragma unroll
      for (int j = 0; j < 4; ++j) {
        const int rr = row0 + m * 16 + j;
        const float v = acc[m][n][j] + bsv;
        const int bb = rr >> 10, s = rr & 1023;
        if (z < 2) qk_dst[((bb * 16 + hh) << 16) + (s << 6) + d] = f2bf(v);
        else       vT[((bb * 16 + hh) << 16) + (d << 10) + s] = f2bf(v);
      }
  }
}

// output projection: d_out = ctx @ Wo^T + bo  (f32 out)
__global__ __launch_bounds__(256) void out_gemm_k(
    const USH* __restrict__ ctx, const USH* __restrict__ Wo,
    const float* __restrict__ bo, float* __restrict__ out) {
  __shared__ USH As[128 * 32];
  __shared__ USH Bs[128 * 32];
  f4v acc[4][4];
#pragma unroll
  for (int m = 0; m < 4; ++m)
#pragma unroll
    for (int n = 0; n < 4; ++n) acc[m][n] = f4v{0.f, 0.f, 0.f, 0.f};
  gemm_mainloop(ctx, Wo, blockIdx.y * 128, blockIdx.x * 128, As, Bs, acc, threadIdx.x);
  const int lane = threadIdx.x & 63, wid = threadIdx.x >> 6;
  const int l15 = lane & 15, lg = lane >> 4;
  const int row0 = blockIdx.y * 128 + (wid >> 1) * 64 + lg * 4;
  const int col0 = blockIdx.x * 128 + (wid & 1) * 64 + l15;
#pragma unroll
  for (int n = 0; n < 4; ++n) {
    const int co = col0 + n * 16;
    const float bsv = bo[co];
#pragma unroll
    for (int m = 0; m < 4; ++m)
#pragma unroll
      for (int j = 0; j < 4; ++j) {
        const int rr = row0 + m * 16 + j;
        out[rr * 1024 + co] = acc[m][n][j] + bsv;
      }
  }
}

// ---------------- flash attention: barrier-free, direct K/V fragment loads ----------------
// grid 1024 (XCD-swizzled (fb,h,b)), 256 threads = 4 independent waves x 16 f-rows.
// K/V fragments loaded straight from global (L2-resident); NO __syncthreads in loop.
__global__ __launch_bounds__(256, 4) void attn_k(
    const USH* __restrict__ qh, const USH* __restrict__ kh, const USH* __restrict__ vT,
    const float* __restrict__ rb, const int* __restrict__ mask, USH* __restrict__ ctx) {
  __shared__ USH Ps[4 * 16 * 72];       // per-wave P[f][t], pad 72 (2-way max, free)

  const int tid = threadIdx.x, lane = tid & 63, w = tid >> 6;
  const int l15 = lane & 15, lg = lane >> 4;
  const int swz = ((blockIdx.x & 7) << 7) | (blockIdx.x >> 3);
  const int fb = swz & 15, h = (swz >> 4) & 15, b = swz >> 8;
  const int bh = b * 16 + h;

  const int f_row = fb * 64 + w * 16 + l15;               // this lane's f (softmax side)
  const USH* qptr = qh + (bh << 16) + f_row * 64 + lg * 8;
  const s8v bq0 = *(const s8v*)qptr;
  const s8v bq1 = *(const s8v*)(qptr + 32);

  f4v acc[4];                                             // [db]: O[f=lg*4+j][d=db*16+l15]
#pragma unroll
  for (int db = 0; db < 4; ++db) acc[db] = f4v{0.f, 0.f, 0.f, 0.f};
  float m_ = -1e30f, l_ = 0.f;                            // per-lane row f_row state

  const USH* kbase = kh + (bh << 16);
  const USH* vbase = vT + (bh << 16);
  const float* bias_b = rb + (h << 20) + (f_row << 10);
  const int* mask_b = mask + (b << 20) + (f_row << 10);
  USH* Pw = Ps + w * 1152;

  // prefetch chunk 0 bias/mask into registers
  float4 bv4[4]; int4 mv4[4];
#pragma unroll
  for (int tb = 0; tb < 4; ++tb) {
    const int t_g = tb * 16 + lg * 4;
    bv4[tb] = *(const float4*)(bias_b + t_g);
    mv4[tb] = *(const int4*)(mask_b + t_g);
  }

  for (int tc = 0; tc < 16; ++tc) {
    const int t0 = tc * 64;
    // K A-fragments direct from global: K[t=t0+tb*16+l15][d-slices]
    s8v ak0[4], ak1[4];
#pragma unroll
    for (int tb = 0; tb < 4; ++tb) {
      const USH* kp = kbase + (t0 + tb * 16 + l15) * 64 + lg * 8;
      ak0[tb] = *(const s8v*)kp;
      ak1[tb] = *(const s8v*)(kp + 32);
    }
    // prefetch next chunk's bias/mask (used ~whole chunk later)
    float4 bn4[4]; int4 mn4[4];
    if (tc < 15) {
#pragma unroll
      for (int tb = 0; tb < 4; ++tb) {
        const int t_g = t0 + 64 + tb * 16 + lg * 4;
        bn4[tb] = *(const float4*)(bias_b + t_g);
        mn4[tb] = *(const int4*)(mask_b + t_g);
      }
    }
    // S^T = K Q^T : lane holds S[t=t0+tb*16+lg*4+j][f=l15]
    f4v sa[4];
    __builtin_amdgcn_s_setprio(1);
#pragma unroll
    for (int tb = 0; tb < 4; ++tb) {
      sa[tb] = f4v{0.f, 0.f, 0.f, 0.f};
      sa[tb] = MFMA16(ak0[tb], bq0, sa[tb]);
      sa[tb] = MFMA16(ak1[tb], bq1, sa[tb]);
    }
    __builtin_amdgcn_s_setprio(0);
    // scale + bias + exact mask-replace (regs prefetched last chunk)
    float sv[4][4];
#pragma unroll
    for (int tb = 0; tb < 4; ++tb) {
      const float* bvp = (const float*)&bv4[tb];
      const int* mvp = (const int*)&mv4[tb];
#pragma unroll
      for (int j = 0; j < 4; ++j)
        sv[tb][j] = mvp[j] ? -10000.f : fmaf(sa[tb][j], 0.125f, bvp[j]);
    }
    // online softmax: 16 values per lane + reduce across lg (xor 16,32)
    float mx = sv[0][0];
#pragma unroll
    for (int tb = 0; tb < 4; ++tb)
#pragma unroll
      for (int j = 0; j < 4; ++j) mx = fmaxf(mx, sv[tb][j]);
    mx = fmaxf(mx, __shfl_xor(mx, 16));
    mx = fmaxf(mx, __shfl_xor(mx, 32));
    const float mn = fmaxf(m_, mx);
    const float al = __expf(m_ - mn);
    m_ = mn;
    float rs = 0.f;
#pragma unroll
    for (int tb = 0; tb < 4; ++tb) {
      ushort4 pk;
      float p0 = __expf(sv[tb][0] - mn), p1 = __expf(sv[tb][1] - mn);
      float p2 = __expf(sv[tb][2] - mn), p3 = __expf(sv[tb][3] - mn);
      rs += (p0 + p1) + (p2 + p3);
      pk.x = f2bf(p0); pk.y = f2bf(p1); pk.z = f2bf(p2); pk.w = f2bf(p3);
      *(ushort4*)(Pw + l15 * 72 + tb * 16 + lg * 4) = pk;
    }
    rs += __shfl_xor(rs, 16);
    rs += __shfl_xor(rs, 32);
    l_ = l_ * al + rs;
    // broadcast al to O-fragment rows (row f-local lg*4+j -> src lane lg*4+j)
    {
      const int rbase = (lane >> 4) << 2;
      const f4v alf = {__shfl(al, rbase), __shfl(al, rbase + 1),
                       __shfl(al, rbase + 2), __shfl(al, rbase + 3)};
#pragma unroll
      for (int db = 0; db < 4; ++db) acc[db] = acc[db] * alf;
    }
    // O += P V : P via per-wave LDS transpose; V B-fragments direct from global
    {
      const USH* Pr = Pw + l15 * 72 + lg * 8;
      const s8v pa0 = *(const s8v*)Pr;
      const s8v pa1 = *(const s8v*)(Pr + 32);
      __builtin_amdgcn_s_setprio(1);
#pragma unroll
      for (int db = 0; db < 4; ++db) {
        const USH* vp = vbase + (db * 16 + l15) * 1024 + t0 + lg * 8;
        acc[db] = MFMA16(pa0, *(const s8v*)vp, acc[db]);
        acc[db] = MFMA16(pa1, *(const s8v*)(vp + 32), acc[db]);
      }
      __builtin_amdgcn_s_setprio(0);
    }
    // rotate bias/mask prefetch
#pragma unroll
    for (int tb = 0; tb < 4; ++tb) { bv4[tb] = bn4[tb]; mv4[tb] = mn4[tb]; }
  }
  // epilogue: ctx[b][f][h*64+d]; row f-local = lg*4+j needs l_ from lane lg*4+j
  const int rbase = (lane >> 4) << 2;
  float inv[4];
#pragma unroll
  for (int j = 0; j < 4; ++j) inv[j] = 1.f / __shfl(l_, rbase + j);
  USH* cbase = ctx + ((size_t)((b << 10) + fb * 64 + w * 16 + lg * 4)) * 1024 + (h << 6) + l15;
#pragma unroll
  for (int db = 0; db < 4; ++db)
#pragma unroll
    for (int j = 0; j < 4; ++j)
      cbase[j * 1024 + db * 16] = f2bf(acc[db][j] * inv[j]);
}

// ---------------- launch ----------------
extern "C" void kernel_launch(void* const* d_in, const int* in_sizes, int n_in,
                              void* d_out, int out_size, void* d_ws, size_t ws_size,
                              hipStream_t stream) {
  const float* q    = (const float*)d_in[0];
  const float* k    = (const float*)d_in[1];
  const float* v    = (const float*)d_in[2];
  const int*   mask = (const int*)d_in[3];
  const float* rb   = (const float*)d_in[4];
  const float* Wq   = (const float*)d_in[5];
  const float* bq   = (const float*)d_in[6];
  const float* Wk   = (const float*)d_in[7];
  const float* bk   = (const float*)d_in[8];
  const float* Wv   = (const float*)d_in[9];
  const float* bv   = (const float*)d_in[10];
  const float* Wo   = (const float*)d_in[11];
  const float* bo   = (const float*)d_in[12];

  char* ws = (char*)d_ws;
  const size_t MB = 1024 * 1024;
  if (ws_size < 64 * MB) return;
  USH* qb    = (USH*)(ws + 0 * MB);
  USH* kb    = (USH*)(ws + 8 * MB);
  USH* vb    = (USH*)(ws + 16 * MB);
  USH* Wqb   = (USH*)(ws + 24 * MB);
  USH* Wkb   = (USH*)(ws + 26 * MB);
  USH* Wvb   = (USH*)(ws + 28 * MB);
  USH* Wob   = (USH*)(ws + 30 * MB);
  USH* qhp   = (USH*)(ws + 32 * MB);   // [B,H,F,64]
  USH* khp   = (USH*)(ws + 40 * MB);   // [B,H,T,64]
  USH* vTp   = (USH*)(ws + 48 * MB);   // [B,H,64,T]
  USH* ctxp  = (USH*)(ws + 56 * MB);   // [B,F,C]

  cvt_qkv_k<<<dim3(4096, 3), 256, 0, stream>>>(q, k, v, qb, kb, vb);
  cvt_w_k<<<dim3(1024, 4), 256, 0, stream>>>(Wq, Wk, Wv, Wo, Wqb, Wkb, Wvb, Wob);
  proj_gemm_k<<<dim3(8, 32, 3), 256, 0, stream>>>(qb, kb, vb, Wqb, Wkb, Wvb, bq, bk, bv,
                                                  qhp, khp, vTp);
  attn_k<<<dim3(1024), 256, 0, stream>>>(qhp, khp, vTp, rb, mask, ctxp);
  out_gemm_k<<<dim3(8, 32), 256, 0, stream>>>(ctxp, Wob, bo, (float*)d_out);
}

// Round 7
// 167.236 us; speedup vs baseline: 1.8073x; 1.8073x over previous
//
#include <hip/hip_runtime.h>

#define USH unsigned short

using s8v = __attribute__((ext_vector_type(8))) short;   // 8 x bf16 (4 VGPR)
using f4v = __attribute__((ext_vector_type(4))) float;   // MFMA accumulator

#define MFMA16(a,b,c) __builtin_amdgcn_mfma_f32_16x16x32_bf16(a,b,c,0,0,0)

// dims: B=4, F=T=1024, C=1024, H=16, D=64

__device__ __forceinline__ USH f2bf(float f) {            // RNE f32->bf16
  unsigned int u = __builtin_bit_cast(unsigned int, f);
  u += 0x7fffu + ((u >> 16) & 1u);
  return (USH)(u >> 16);
}
__device__ __forceinline__ void gload16(const void* g, void* l) {
  __builtin_amdgcn_global_load_lds((const __attribute__((address_space(1))) void*)g,
                                   (__attribute__((address_space(3))) void*)l, 16, 0, 0);
}

// ---------------- conversion kernels ----------------
__global__ __launch_bounds__(256) void cvt_qkv_k(
    const float* __restrict__ q, const float* __restrict__ k, const float* __restrict__ v,
    USH* __restrict__ oq, USH* __restrict__ ok, USH* __restrict__ ov) {
  const int which = blockIdx.y;
  const float* in = which == 0 ? q : (which == 1 ? k : v);
  USH* out = which == 0 ? oq : (which == 1 ? ok : ov);
  const int i = blockIdx.x * 256 + threadIdx.x;           // n4 = 1<<20
  float4 val = ((const float4*)in)[i];
  ushort4 o; o.x = f2bf(val.x); o.y = f2bf(val.y); o.z = f2bf(val.z); o.w = f2bf(val.w);
  ((ushort4*)out)[i] = o;
}

__global__ __launch_bounds__(256) void cvt_w_k(
    const float* __restrict__ a, const float* __restrict__ b,
    const float* __restrict__ c, const float* __restrict__ d,
    USH* __restrict__ oa, USH* __restrict__ ob, USH* __restrict__ oc, USH* __restrict__ od) {
  const int which = blockIdx.y;
  const float* in = which == 0 ? a : which == 1 ? b : which == 2 ? c : d;
  USH* out = which == 0 ? oa : which == 1 ? ob : which == 2 ? oc : od;
  const int i = blockIdx.x * 256 + threadIdx.x;           // n4 = 262144
  float4 val = ((const float4*)in)[i];
  ushort4 o; o.x = f2bf(val.x); o.y = f2bf(val.y); o.z = f2bf(val.z); o.w = f2bf(val.w);
  ((ushort4*)out)[i] = o;
}

// ---------------- GEMM core: 128x128 tile, BK=32, K=1024, B^T layout ----------------
__device__ __forceinline__ void gemm_mainloop(
    const USH* __restrict__ A, const USH* __restrict__ W,
    int rowA0, int colW0, USH* As, USH* Bs, f4v acc[4][4], int tid) {
  const int lane = tid & 63;
  const int wid = tid >> 6;
  const int l15 = lane & 15, lg = lane >> 4;
  const int wr = (wid >> 1) * 64, wc = (wid & 1) * 64;
  for (int kk = 0; kk < 32; ++kk) {
    const int k0 = kk * 32;
    {                                                     // stage 8KB A + 8KB W
      const int c0 = tid, c1 = 256 + tid;
      gload16(A + (rowA0 + (c0 >> 2)) * 1024 + k0 + (c0 & 3) * 8, As + c0 * 8);
      gload16(A + (rowA0 + (c1 >> 2)) * 1024 + k0 + (c1 & 3) * 8, As + c1 * 8);
      gload16(W + (colW0 + (c0 >> 2)) * 1024 + k0 + (c0 & 3) * 8, Bs + c0 * 8);
      gload16(W + (colW0 + (c1 >> 2)) * 1024 + k0 + (c1 & 3) * 8, Bs + c1 * 8);
    }
    __syncthreads();
    s8v a[4], b[4];
    const USH* ap = As + (wr + l15) * 32 + lg * 8;
    const USH* bp = Bs + (wc + l15) * 32 + lg * 8;
#pragma unroll
    for (int m = 0; m < 4; ++m) a[m] = *(const s8v*)(ap + m * 512);
#pragma unroll
    for (int n = 0; n < 4; ++n) b[n] = *(const s8v*)(bp + n * 512);
#pragma unroll
    for (int m = 0; m < 4; ++m)
#pragma unroll
      for (int n = 0; n < 4; ++n)
        acc[m][n] = MFMA16(a[m], b[n], acc[m][n]);
    __syncthreads();
  }
}

// fused Q/K/V projection; z selects which. Q/K -> [B,H,S,64]; V -> [B,H,64,T] (transposed)
__global__ __launch_bounds__(256) void proj_gemm_k(
    const USH* __restrict__ qb, const USH* __restrict__ kb, const USH* __restrict__ vb,
    const USH* __restrict__ Wq, const USH* __restrict__ Wk, const USH* __restrict__ Wv,
    const float* __restrict__ bq, const float* __restrict__ bk, const float* __restrict__ bv,
    USH* __restrict__ qh, USH* __restrict__ kh, USH* __restrict__ vT) {
  __shared__ USH As[128 * 32];
  __shared__ USH Bs[128 * 32];
  const int z = blockIdx.z;
  const USH* A = z == 0 ? qb : (z == 1 ? kb : vb);
  const USH* W = z == 0 ? Wq : (z == 1 ? Wk : Wv);
  const float* bias = z == 0 ? bq : (z == 1 ? bk : bv);
  f4v acc[4][4];
#pragma unroll
  for (int m = 0; m < 4; ++m)
#pragma unroll
    for (int n = 0; n < 4; ++n) acc[m][n] = f4v{0.f, 0.f, 0.f, 0.f};
  gemm_mainloop(A, W, blockIdx.y * 128, blockIdx.x * 128, As, Bs, acc, threadIdx.x);
  const int lane = threadIdx.x & 63, wid = threadIdx.x >> 6;
  const int l15 = lane & 15, lg = lane >> 4;
  const int row0 = blockIdx.y * 128 + (wid >> 1) * 64 + lg * 4;
  const int col0 = blockIdx.x * 128 + (wid & 1) * 64 + l15;
  USH* qk_dst = (z == 0) ? qh : kh;
#pragma unroll
  for (int n = 0; n < 4; ++n) {
    const int co = col0 + n * 16;
    const float bsv = bias[co];
    const int hh = co >> 6, d = co & 63;
#pragma unroll
    for (int m = 0; m < 4; ++m)
#pragma unroll
      for (int j = 0; j < 4; ++j) {
        const int rr = row0 + m * 16 + j;
        const float v = acc[m][n][j] + bsv;
        const int bb = rr >> 10, s = rr & 1023;
        if (z < 2) qk_dst[((bb * 16 + hh) << 16) + (s << 6) + d] = f2bf(v);
        else       vT[((bb * 16 + hh) << 16) + (d << 10) + s] = f2bf(v);
      }
  }
}

// output projection: d_out = ctx @ Wo^T + bo  (f32 out)
__global__ __launch_bounds__(256) void out_gemm_k(
    const USH* __restrict__ ctx, const USH* __restrict__ Wo,
    const float* __restrict__ bo, float* __restrict__ out) {
  __shared__ USH As[128 * 32];
  __shared__ USH Bs[128 * 32];
  f4v acc[4][4];
#pragma unroll
  for (int m = 0; m < 4; ++m)
#pragma unroll
    for (int n = 0; n < 4; ++n) acc[m][n] = f4v{0.f, 0.f, 0.f, 0.f};
  gemm_mainloop(ctx, Wo, blockIdx.y * 128, blockIdx.x * 128, As, Bs, acc, threadIdx.x);
  const int lane = threadIdx.x & 63, wid = threadIdx.x >> 6;
  const int l15 = lane & 15, lg = lane >> 4;
  const int row0 = blockIdx.y * 128 + (wid >> 1) * 64 + lg * 4;
  const int col0 = blockIdx.x * 128 + (wid & 1) * 64 + l15;
#pragma unroll
  for (int n = 0; n < 4; ++n) {
    const int co = col0 + n * 16;
    const float bsv = bo[co];
#pragma unroll
    for (int m = 0; m < 4; ++m)
#pragma unroll
      for (int j = 0; j < 4; ++j) {
        const int rr = row0 + m * 16 + j;
        out[rr * 1024 + co] = acc[m][n][j] + bsv;
      }
  }
}

// ---------------- flash attention (S^T form, R3 structure + bias/mask reg-prefetch) ----------------
// grid: 1024 blocks (XCD-swizzled (fb,h,b)), 256 threads = 4 waves x 16 f-rows.
// Per chunk: stage K/V -> barrier -> [issue next chunk's bias/mask loads] -> compute -> barrier.
__global__ __launch_bounds__(256) void attn_k(
    const USH* __restrict__ qh, const USH* __restrict__ kh, const USH* __restrict__ vT,
    const float* __restrict__ rb, const int* __restrict__ mask, USH* __restrict__ ctx) {
  __shared__ USH Ks[64 * 64];           // [t][d], col8 XOR-swizzled by (t&7)
  __shared__ USH Vs[64 * 64];           // [d][t], col8 XOR-swizzled by (d&7)
  __shared__ USH Ps[4 * 16 * 72];       // per-wave P[f][t], pad 72

  const int tid = threadIdx.x, lane = tid & 63, w = tid >> 6;
  const int l15 = lane & 15, lg = lane >> 4;
  const int swz = ((blockIdx.x & 7) << 7) | (blockIdx.x >> 3);
  const int fb = swz & 15, h = (swz >> 4) & 15, b = swz >> 8;
  const int bh = b * 16 + h;

  const int f_row = fb * 64 + w * 16 + l15;               // this lane's f (softmax side)
  const USH* qptr = qh + (bh << 16) + f_row * 64 + lg * 8;
  const s8v bq0 = *(const s8v*)qptr;
  const s8v bq1 = *(const s8v*)(qptr + 32);

  f4v acc[4];                                             // [db]: O[f=lg*4+j][d=db*16+l15]
#pragma unroll
  for (int db = 0; db < 4; ++db) acc[db] = f4v{0.f, 0.f, 0.f, 0.f};
  float m_ = -1e30f, l_ = 0.f;                            // per-lane row f_row state

  const USH* kbase = kh + (bh << 16);
  const USH* vbase = vT + (bh << 16);
  const float* bias_b = rb + (h << 20) + (f_row << 10);
  const int* mask_b = mask + (b << 20) + (f_row << 10);

  // staging slots: this thread fills slots tid and tid+256 of each of Ks, Vs
  const int c0 = tid, c1 = tid + 256;
  const int kr0 = c0 >> 3, kc0 = ((c0 & 7) ^ (kr0 & 7)) * 8;
  const int kr1 = c1 >> 3, kc1 = ((c1 & 7) ^ (kr1 & 7)) * 8;

  // prologue: prefetch chunk 0 bias/mask into registers
  float4 bv4[4]; int4 mv4[4];
#pragma unroll
  for (int tb = 0; tb < 4; ++tb) {
    const int t_g = tb * 16 + lg * 4;
    bv4[tb] = *(const float4*)(bias_b + t_g);
    mv4[tb] = *(const int4*)(mask_b + t_g);
  }
  float4 bn4[4]; int4 mn4[4];

  for (int tc = 0; tc < 16; ++tc) {
    const int t0 = tc * 64;
    {
      gload16(kbase + (t0 + kr0) * 64 + kc0, Ks + c0 * 8);
      gload16(kbase + (t0 + kr1) * 64 + kc1, Ks + c1 * 8);
      gload16(vbase + kr0 * 1024 + t0 + kc0, Vs + c0 * 8);
      gload16(vbase + kr1 * 1024 + t0 + kc1, Vs + c1 * 8);
    }
    __syncthreads();
    // issue NEXT chunk's bias/mask loads right after the barrier: they get the whole
    // compute phase + next staging (~1 chunk ≈ HBM latency) before any drain point.
    if (tc < 15) {
#pragma unroll
      for (int tb = 0; tb < 4; ++tb) {
        const int t_g = t0 + 64 + tb * 16 + lg * 4;
        bn4[tb] = *(const float4*)(bias_b + t_g);
        mn4[tb] = *(const int4*)(mask_b + t_g);
      }
    }
    // S^T = K Q^T : lane holds S[t=t0+tb*16+lg*4+j][f=l15]
    f4v sa[4];
    const int sw = (l15 & 7);
    __builtin_amdgcn_s_setprio(1);
#pragma unroll
    for (int tb = 0; tb < 4; ++tb) {
      sa[tb] = f4v{0.f, 0.f, 0.f, 0.f};
      const USH* kp = Ks + (tb * 16 + l15) * 64;
      sa[tb] = MFMA16(*(const s8v*)(kp + ((lg ^ sw) * 8)), bq0, sa[tb]);
      sa[tb] = MFMA16(*(const s8v*)(kp + (((lg + 4) ^ sw) * 8)), bq1, sa[tb]);
    }
    __builtin_amdgcn_s_setprio(0);
    // scale + bias + exact mask-replace (bias/mask prefetched last chunk)
    float sv[4][4];
#pragma unroll
    for (int tb = 0; tb < 4; ++tb) {
      const float* bvp = (const float*)&bv4[tb];
      const int* mvp = (const int*)&mv4[tb];
#pragma unroll
      for (int j = 0; j < 4; ++j)
        sv[tb][j] = mvp[j] ? -10000.f : fmaf(sa[tb][j], 0.125f, bvp[j]);
    }
    // online softmax: 16 values per lane + reduce across lg (xor 16,32)
    float mx = sv[0][0];
#pragma unroll
    for (int tb = 0; tb < 4; ++tb)
#pragma unroll
      for (int j = 0; j < 4; ++j) mx = fmaxf(mx, sv[tb][j]);
    mx = fmaxf(mx, __shfl_xor(mx, 16));
    mx = fmaxf(mx, __shfl_xor(mx, 32));
    const float mn = fmaxf(m_, mx);
    const float al = __expf(m_ - mn);
    m_ = mn;
    float rs = 0.f;
    USH* Pw = Ps + w * 1152 + l15 * 72;
#pragma unroll
    for (int tb = 0; tb < 4; ++tb) {
      ushort4 pk;
      float p0 = __expf(sv[tb][0] - mn), p1 = __expf(sv[tb][1] - mn);
      float p2 = __expf(sv[tb][2] - mn), p3 = __expf(sv[tb][3] - mn);
      rs += (p0 + p1) + (p2 + p3);
      pk.x = f2bf(p0); pk.y = f2bf(p1); pk.z = f2bf(p2); pk.w = f2bf(p3);
      *(ushort4*)(Pw + tb * 16 + lg * 4) = pk;
    }
    rs += __shfl_xor(rs, 16);
    rs += __shfl_xor(rs, 32);
    l_ = l_ * al + rs;
    // broadcast al to O-fragment rows (row f-local = lg*4+j lives at src lane lg*4+j)
    {
      const int rbase = (lane >> 4) << 2;
      const f4v alf = {__shfl(al, rbase), __shfl(al, rbase + 1),
                       __shfl(al, rbase + 2), __shfl(al, rbase + 3)};
#pragma unroll
      for (int db = 0; db < 4; ++db) acc[db] = acc[db] * alf;
    }
    // O += P V : A = P rows f (per-wave LDS), B = V^T rows d (swizzled Vs)
    {
      const USH* Pr = Ps + w * 1152 + l15 * 72 + lg * 8;
      const s8v pa0 = *(const s8v*)Pr;
      const s8v pa1 = *(const s8v*)(Pr + 32);
      __builtin_amdgcn_s_setprio(1);
#pragma unroll
      for (int db = 0; db < 4; ++db) {
        const USH* vp = Vs + (db * 16 + l15) * 64;
        acc[db] = MFMA16(pa0, *(const s8v*)(vp + ((lg ^ sw) * 8)), acc[db]);
        acc[db] = MFMA16(pa1, *(const s8v*)(vp + (((lg + 4) ^ sw) * 8)), acc[db]);
      }
      __builtin_amdgcn_s_setprio(0);
    }
    __syncthreads();
    // rotate the prefetched registers into place for the next chunk
#pragma unroll
    for (int tb = 0; tb < 4; ++tb) { bv4[tb] = bn4[tb]; mv4[tb] = mn4[tb]; }
  }
  // epilogue: ctx[b][f][h*64+d]; row f-local = lg*4+j needs l_ from lane lg*4+j
  const int rbase = (lane >> 4) << 2;
  float inv[4];
#pragma unroll
  for (int j = 0; j < 4; ++j) inv[j] = 1.f / __shfl(l_, rbase + j);
  USH* cbase = ctx + ((size_t)((b << 10) + fb * 64 + w * 16 + lg * 4)) * 1024 + (h << 6) + l15;
#pragma unroll
  for (int db = 0; db < 4; ++db)
#pragma unroll
    for (int j = 0; j < 4; ++j)
      cbase[j * 1024 + db * 16] = f2bf(acc[db][j] * inv[j]);
}

// ---------------- launch ----------------
extern "C" void kernel_launch(void* const* d_in, const int* in_sizes, int n_in,
                              void* d_out, int out_size, void* d_ws, size_t ws_size,
                              hipStream_t stream) {
  const float* q    = (const float*)d_in[0];
  const float* k    = (const float*)d_in[1];
  const float* v    = (const float*)d_in[2];
  const int*   mask = (const int*)d_in[3];
  const float* rb   = (const float*)d_in[4];
  const float* Wq   = (const float*)d_in[5];
  const float* bq   = (const float*)d_in[6];
  const float* Wk   = (const float*)d_in[7];
  const float* bk   = (const float*)d_in[8];
  const float* Wv   = (const float*)d_in[9];
  const float* bv   = (const float*)d_in[10];
  const float* Wo   = (const float*)d_in[11];
  const float* bo   = (const float*)d_in[12];

  char* ws = (char*)d_ws;
  const size_t MB = 1024 * 1024;
  if (ws_size < 64 * MB) return;
  USH* qb    = (USH*)(ws + 0 * MB);
  USH* kb    = (USH*)(ws + 8 * MB);
  USH* vb    = (USH*)(ws + 16 * MB);
  USH* Wqb   = (USH*)(ws + 24 * MB);
  USH* Wkb   = (USH*)(ws + 26 * MB);
  USH* Wvb   = (USH*)(ws + 28 * MB);
  USH* Wob   = (USH*)(ws + 30 * MB);
  USH* qhp   = (USH*)(ws + 32 * MB);   // [B,H,F,64]
  USH* khp   = (USH*)(ws + 40 * MB);   // [B,H,T,64]
  USH* vTp   = (USH*)(ws + 48 * MB);   // [B,H,64,T]
  USH* ctxp  = (USH*)(ws + 56 * MB);   // [B,F,C]

  cvt_qkv_k<<<dim3(4096, 3), 256, 0, stream>>>(q, k, v, qb, kb, vb);
  cvt_w_k<<<dim3(1024, 4), 256, 0, stream>>>(Wq, Wk, Wv, Wo, Wqb, Wkb, Wvb, Wob);
  proj_gemm_k<<<dim3(8, 32, 3), 256, 0, stream>>>(qb, kb, vb, Wqb, Wkb, Wvb, bq, bk, bv,
                                                  qhp, khp, vTp);
  attn_k<<<dim3(1024), 256, 0, stream>>>(qhp, khp, vTp, rb, mask, ctxp);
  out_gemm_k<<<dim3(8, 32), 256, 0, stream>>>(ctxp, Wob, bo, (float*)d_out);
}